// Round 3
// baseline (1787.215 us; speedup 1.0000x reference)
//
#include <hip/hip_runtime.h>
#include <math.h>

#define NJ 24
#define TPB 256
#define VPT 4
#define VPB (TPB * VPT)  // 1024 vertices per block

__device__ __constant__ int PAR[NJ] = {-1,0,0,0,1,2,3,4,5,6,7,8,9,9,9,12,13,14,16,17,18,19,20,21};
// Root-first ancestor chain (including self), padded with -1.
__device__ __constant__ int CHAIN[NJ][9] = {
  {0,-1,-1,-1,-1,-1,-1,-1,-1},
  {0, 1,-1,-1,-1,-1,-1,-1,-1},
  {0, 2,-1,-1,-1,-1,-1,-1,-1},
  {0, 3,-1,-1,-1,-1,-1,-1,-1},
  {0, 1, 4,-1,-1,-1,-1,-1,-1},
  {0, 2, 5,-1,-1,-1,-1,-1,-1},
  {0, 3, 6,-1,-1,-1,-1,-1,-1},
  {0, 1, 4, 7,-1,-1,-1,-1,-1},
  {0, 2, 5, 8,-1,-1,-1,-1,-1},
  {0, 3, 6, 9,-1,-1,-1,-1,-1},
  {0, 1, 4, 7,10,-1,-1,-1,-1},
  {0, 2, 5, 8,11,-1,-1,-1,-1},
  {0, 3, 6, 9,12,-1,-1,-1,-1},
  {0, 3, 6, 9,13,-1,-1,-1,-1},
  {0, 3, 6, 9,14,-1,-1,-1,-1},
  {0, 3, 6, 9,12,15,-1,-1,-1},
  {0, 3, 6, 9,13,16,-1,-1,-1},
  {0, 3, 6, 9,14,17,-1,-1,-1},
  {0, 3, 6, 9,13,16,18,-1,-1},
  {0, 3, 6, 9,14,17,19,-1,-1},
  {0, 3, 6, 9,13,16,18,20,-1},
  {0, 3, 6, 9,14,17,19,21,-1},
  {0, 3, 6, 9,13,16,18,20,22},
  {0, 3, 6, 9,14,17,19,21,23},
};

// ---- device helpers shared by both FK paths ----

__device__ __forceinline__ void fk_local(const float* __restrict__ J_hat,
                                         const float* __restrict__ pose,
                                         int b, int j, float* __restrict__ L /*12*/)
{
  const float rx = pose[b * 72 + j * 3 + 0];
  const float ry = pose[b * 72 + j * 3 + 1];
  const float rz = pose[b * 72 + j * 3 + 2];
  const float theta = sqrtf(rx * rx + ry * ry + rz * rz) + 1e-8f;
  const float inv = 1.0f / theta;
  const float ux = rx * inv, uy = ry * inv, uz = rz * inv;
  const float c = cosf(theta), s = sinf(theta);
  const float ic = 1.0f - c;

  float tx = J_hat[j * 3 + 0];
  float ty = J_hat[j * 3 + 1];
  float tz = J_hat[j * 3 + 2];
  const int p = PAR[j];
  if (p >= 0) {
    tx -= J_hat[p * 3 + 0];
    ty -= J_hat[p * 3 + 1];
    tz -= J_hat[p * 3 + 2];
  }

  L[0]  = c + ic * ux * ux;
  L[1]  = ic * ux * uy - s * uz;
  L[2]  = ic * ux * uz + s * uy;
  L[3]  = tx;
  L[4]  = ic * uy * ux + s * uz;
  L[5]  = c + ic * uy * uy;
  L[6]  = ic * uy * uz - s * ux;
  L[7]  = ty;
  L[8]  = ic * uz * ux - s * uy;
  L[9]  = ic * uz * uy + s * ux;
  L[10] = c + ic * uz * uz;
  L[11] = tz;
}

__device__ __forceinline__ void fk_compose(const float (*__restrict__ Lc)[12],
                                           const float* __restrict__ J_hat,
                                           int j, float* __restrict__ g /*12*/)
{
#pragma unroll
  for (int k = 0; k < 12; k++) g[k] = Lc[0][k];
#pragma unroll
  for (int d = 1; d < 9; d++) {
    const int a = CHAIN[j][d];
    if (a >= 0) {
      float l[12];
#pragma unroll
      for (int k = 0; k < 12; k++) l[k] = Lc[a][k];
      float n[12];
#pragma unroll
      for (int r = 0; r < 3; r++) {
        const float gr0 = g[r * 4 + 0], gr1 = g[r * 4 + 1], gr2 = g[r * 4 + 2];
        n[r * 4 + 0] = gr0 * l[0] + gr1 * l[4] + gr2 * l[8];
        n[r * 4 + 1] = gr0 * l[1] + gr1 * l[5] + gr2 * l[9];
        n[r * 4 + 2] = gr0 * l[2] + gr1 * l[6] + gr2 * l[10];
        n[r * 4 + 3] = gr0 * l[3] + gr1 * l[7] + gr2 * l[11] + g[r * 4 + 3];
      }
#pragma unroll
      for (int k = 0; k < 12; k++) g[k] = n[k];
    }
  }
  // subtract rest-pose joint location: t' = t - R_g @ J_hat[j]
  const float jx = J_hat[j * 3 + 0], jy = J_hat[j * 3 + 1], jz = J_hat[j * 3 + 2];
  g[3]  -= g[0] * jx + g[1] * jy + g[2]  * jz;
  g[7]  -= g[4] * jx + g[5] * jy + g[6]  * jz;
  g[11] -= g[8] * jx + g[9] * jy + g[10] * jz;
}

// ---- kernel 1: forward kinematics, one wave per batch element ----
__global__ __launch_bounds__(64) void smpl_fk_kernel(
    const float* __restrict__ J_hat,
    const float* __restrict__ pose,
    float* __restrict__ Gws)   // (B, 24, 12)
{
  __shared__ __align__(16) float Lc[NJ][12];
  const int b = blockIdx.x;
  const int tid = threadIdx.x;

  if (tid < NJ) {
    float L[12];
    fk_local(J_hat, pose, b, tid, L);
#pragma unroll
    for (int k = 0; k < 12; k++) Lc[tid][k] = L[k];
  }
  __syncthreads();
  if (tid < NJ) {
    float g[12];
    fk_compose(Lc, J_hat, tid, g);
    float* dst = Gws + (size_t)b * (NJ * 12) + tid * 12;
#pragma unroll
    for (int k = 0; k < 12; k++) dst[k] = g[k];
  }
}

// ---- kernel 2: linear blend skinning ----
// blockIdx.y = batch, blockIdx.x = vertex chunk. G' either loaded from Gws
// (FROM_WS) or rebuilt inline (fallback when ws is too small).
template <bool FROM_WS>
__global__ __launch_bounds__(TPB, 4) void smpl_blend_kernel(
    const float* __restrict__ T_hat,
    const float* __restrict__ J_hat,
    const float* __restrict__ weights,
    const float* __restrict__ pose,
    const float* __restrict__ trans,
    const float* __restrict__ Gws,
    float* __restrict__ out,
    int V)
{
  __shared__ __align__(16) float Gm[NJ][12];  // 288 floats, contiguous

  const int b = blockIdx.y;
  const int tid = threadIdx.x;

  if constexpr (FROM_WS) {
    if (tid < 72) {
      const float4 g = *reinterpret_cast<const float4*>(
          Gws + (size_t)b * (NJ * 12) + tid * 4);
      *reinterpret_cast<float4*>(&Gm[0][0] + tid * 4) = g;
    }
  } else {
    __shared__ __align__(16) float Lc[NJ][12];
    if (tid < NJ) {
      float L[12];
      fk_local(J_hat, pose, b, tid, L);
#pragma unroll
      for (int k = 0; k < 12; k++) Lc[tid][k] = L[k];
    }
    __syncthreads();
    if (tid < NJ) {
      float g[12];
      fk_compose(Lc, J_hat, tid, g);
#pragma unroll
      for (int k = 0; k < 12; k++) Gm[tid][k] = g[k];
    }
  }
  __syncthreads();

  const float t0 = trans[b * 3 + 0];
  const float t1 = trans[b * 3 + 1];
  const float t2 = trans[b * 3 + 2];
  float* __restrict__ outb = out + (size_t)b * V * 3;

  const int v0 = blockIdx.x * VPB + tid * VPT;  // v0 % 4 == 0 always
  if (v0 >= V) return;

  if (v0 + VPT <= V) {
    float acc[VPT][12];
    const float* wbase = weights + (size_t)v0 * 24;

    // j in chunks of 4: one float4 of weights per vertex per chunk,
    // 3x float4 broadcast reads of G per joint from LDS.
#pragma unroll
    for (int jc = 0; jc < 6; jc++) {
      float4 w4[VPT];
#pragma unroll
      for (int i = 0; i < VPT; i++)
        w4[i] = *reinterpret_cast<const float4*>(wbase + i * 24 + jc * 4);
#pragma unroll
      for (int jj = 0; jj < 4; jj++) {
        const int j = jc * 4 + jj;
        const float4 g0 = *reinterpret_cast<const float4*>(&Gm[j][0]);
        const float4 g1 = *reinterpret_cast<const float4*>(&Gm[j][4]);
        const float4 g2 = *reinterpret_cast<const float4*>(&Gm[j][8]);
#pragma unroll
        for (int i = 0; i < VPT; i++) {
          const float w = (jj == 0) ? w4[i].x : (jj == 1) ? w4[i].y
                        : (jj == 2) ? w4[i].z : w4[i].w;
          if (jc == 0 && jj == 0) {
            acc[i][0]  = w * g0.x;  acc[i][1]  = w * g0.y;
            acc[i][2]  = w * g0.z;  acc[i][3]  = w * g0.w;
            acc[i][4]  = w * g1.x;  acc[i][5]  = w * g1.y;
            acc[i][6]  = w * g1.z;  acc[i][7]  = w * g1.w;
            acc[i][8]  = w * g2.x;  acc[i][9]  = w * g2.y;
            acc[i][10] = w * g2.z;  acc[i][11] = w * g2.w;
          } else {
            acc[i][0]  = fmaf(w, g0.x, acc[i][0]);
            acc[i][1]  = fmaf(w, g0.y, acc[i][1]);
            acc[i][2]  = fmaf(w, g0.z, acc[i][2]);
            acc[i][3]  = fmaf(w, g0.w, acc[i][3]);
            acc[i][4]  = fmaf(w, g1.x, acc[i][4]);
            acc[i][5]  = fmaf(w, g1.y, acc[i][5]);
            acc[i][6]  = fmaf(w, g1.z, acc[i][6]);
            acc[i][7]  = fmaf(w, g1.w, acc[i][7]);
            acc[i][8]  = fmaf(w, g2.x, acc[i][8]);
            acc[i][9]  = fmaf(w, g2.y, acc[i][9]);
            acc[i][10] = fmaf(w, g2.z, acc[i][10]);
            acc[i][11] = fmaf(w, g2.w, acc[i][11]);
          }
        }
      }
    }

    // T_hat: 12 contiguous floats, 16B-aligned (v0 % 4 == 0)
    float th[3 * VPT];
    const float4* tp = reinterpret_cast<const float4*>(T_hat + (size_t)v0 * 3);
#pragma unroll
    for (int q = 0; q < 3; q++) {
      const float4 t = tp[q];
      th[q * 4 + 0] = t.x; th[q * 4 + 1] = t.y;
      th[q * 4 + 2] = t.z; th[q * 4 + 3] = t.w;
    }

    float o[3 * VPT];
#pragma unroll
    for (int i = 0; i < VPT; i++) {
      const float x = th[i * 3 + 0], y = th[i * 3 + 1], z = th[i * 3 + 2];
      o[i * 3 + 0] = acc[i][0] * x + acc[i][1] * y + acc[i][2]  * z + acc[i][3]  + t0;
      o[i * 3 + 1] = acc[i][4] * x + acc[i][5] * y + acc[i][6]  * z + acc[i][7]  + t1;
      o[i * 3 + 2] = acc[i][8] * x + acc[i][9] * y + acc[i][10] * z + acc[i][11] + t2;
    }
    float4* op = reinterpret_cast<float4*>(outb + (size_t)v0 * 3);
#pragma unroll
    for (int q = 0; q < 3; q++)
      op[q] = make_float4(o[q * 4 + 0], o[q * 4 + 1], o[q * 4 + 2], o[q * 4 + 3]);
  } else {
    // tail: per-vertex scalar path (last 2 vertices: 6890 % 4 == 2)
    for (int v = v0; v < V; v++) {
      float acc[12];
#pragma unroll
      for (int k = 0; k < 12; k++) acc[k] = 0.0f;
      const float* wv = weights + (size_t)v * 24;
#pragma unroll
      for (int j = 0; j < NJ; j++) {
        const float w = wv[j];
#pragma unroll
        for (int k = 0; k < 12; k++) acc[k] = fmaf(w, Gm[j][k], acc[k]);
      }
      const float x = T_hat[v * 3 + 0], y = T_hat[v * 3 + 1], z = T_hat[v * 3 + 2];
      outb[v * 3 + 0] = acc[0] * x + acc[1] * y + acc[2]  * z + acc[3]  + t0;
      outb[v * 3 + 1] = acc[4] * x + acc[5] * y + acc[6]  * z + acc[7]  + t1;
      outb[v * 3 + 2] = acc[8] * x + acc[9] * y + acc[10] * z + acc[11] + t2;
    }
  }
}

extern "C" void kernel_launch(void* const* d_in, const int* in_sizes, int n_in,
                              void* d_out, int out_size, void* d_ws, size_t ws_size,
                              hipStream_t stream) {
  const float* T_hat   = (const float*)d_in[0];
  const float* J_hat   = (const float*)d_in[1];
  const float* weights = (const float*)d_in[2];
  const float* pose    = (const float*)d_in[3];
  const float* trans   = (const float*)d_in[4];
  float* out = (float*)d_out;

  const int V = in_sizes[0] / 3;   // 6890
  const int B = in_sizes[3] / 72;  // 512

  const int nvchunks = (V + VPB - 1) / VPB;  // 7
  dim3 grid(nvchunks, B);

  const size_t ws_needed = (size_t)B * NJ * 12 * sizeof(float);  // 576 KB
  if (ws_size >= ws_needed) {
    float* Gws = (float*)d_ws;
    smpl_fk_kernel<<<B, 64, 0, stream>>>(J_hat, pose, Gws);
    smpl_blend_kernel<true><<<grid, TPB, 0, stream>>>(
        T_hat, J_hat, weights, pose, trans, Gws, out, V);
  } else {
    smpl_blend_kernel<false><<<grid, TPB, 0, stream>>>(
        T_hat, J_hat, weights, pose, trans, nullptr, out, V);
  }
}

// Round 4
// 83.038 us; speedup vs baseline: 21.5229x; 21.5229x over previous
//
#include <hip/hip_runtime.h>
#include <math.h>

#define NJ 24
#define TPB 256
#define VPT 2
#define VPB (TPB * VPT)   // 512 vertices per block
#define FK_BPB 8          // batches per FK block

__device__ __constant__ int PAR[NJ] = {-1,0,0,0,1,2,3,4,5,6,7,8,9,9,9,12,13,14,16,17,18,19,20,21};
// Root-first ancestor chain (including self), padded with -1.
__device__ __constant__ int CHAIN[NJ][9] = {
  {0,-1,-1,-1,-1,-1,-1,-1,-1},
  {0, 1,-1,-1,-1,-1,-1,-1,-1},
  {0, 2,-1,-1,-1,-1,-1,-1,-1},
  {0, 3,-1,-1,-1,-1,-1,-1,-1},
  {0, 1, 4,-1,-1,-1,-1,-1,-1},
  {0, 2, 5,-1,-1,-1,-1,-1,-1},
  {0, 3, 6,-1,-1,-1,-1,-1,-1},
  {0, 1, 4, 7,-1,-1,-1,-1,-1},
  {0, 2, 5, 8,-1,-1,-1,-1,-1},
  {0, 3, 6, 9,-1,-1,-1,-1,-1},
  {0, 1, 4, 7,10,-1,-1,-1,-1},
  {0, 2, 5, 8,11,-1,-1,-1,-1},
  {0, 3, 6, 9,12,-1,-1,-1,-1},
  {0, 3, 6, 9,13,-1,-1,-1,-1},
  {0, 3, 6, 9,14,-1,-1,-1,-1},
  {0, 3, 6, 9,12,15,-1,-1,-1},
  {0, 3, 6, 9,13,16,-1,-1,-1},
  {0, 3, 6, 9,14,17,-1,-1,-1},
  {0, 3, 6, 9,13,16,18,-1,-1},
  {0, 3, 6, 9,14,17,19,-1,-1},
  {0, 3, 6, 9,13,16,18,20,-1},
  {0, 3, 6, 9,14,17,19,21,-1},
  {0, 3, 6, 9,13,16,18,20,22},
  {0, 3, 6, 9,14,17,19,21,23},
};

// ---- device helpers ----

__device__ __forceinline__ void fk_local(const float* __restrict__ J_hat,
                                         const float* __restrict__ pose,
                                         int b, int j, float* __restrict__ L /*12*/)
{
  const float rx = pose[b * 72 + j * 3 + 0];
  const float ry = pose[b * 72 + j * 3 + 1];
  const float rz = pose[b * 72 + j * 3 + 2];
  const float theta = sqrtf(rx * rx + ry * ry + rz * rz) + 1e-8f;
  const float inv = 1.0f / theta;
  const float ux = rx * inv, uy = ry * inv, uz = rz * inv;
  const float c = cosf(theta), s = sinf(theta);
  const float ic = 1.0f - c;

  float tx = J_hat[j * 3 + 0];
  float ty = J_hat[j * 3 + 1];
  float tz = J_hat[j * 3 + 2];
  const int p = PAR[j];
  if (p >= 0) {
    tx -= J_hat[p * 3 + 0];
    ty -= J_hat[p * 3 + 1];
    tz -= J_hat[p * 3 + 2];
  }

  L[0]  = c + ic * ux * ux;
  L[1]  = ic * ux * uy - s * uz;
  L[2]  = ic * ux * uz + s * uy;
  L[3]  = tx;
  L[4]  = ic * uy * ux + s * uz;
  L[5]  = c + ic * uy * uy;
  L[6]  = ic * uy * uz - s * ux;
  L[7]  = ty;
  L[8]  = ic * uz * ux - s * uy;
  L[9]  = ic * uz * uy + s * ux;
  L[10] = c + ic * uz * uz;
  L[11] = tz;
}

__device__ __forceinline__ void fk_compose(const float (*__restrict__ Lc)[12],
                                           const float* __restrict__ J_hat,
                                           int j, float* __restrict__ g /*12*/)
{
#pragma unroll
  for (int k = 0; k < 12; k++) g[k] = Lc[0][k];
#pragma unroll
  for (int d = 1; d < 9; d++) {
    const int a = CHAIN[j][d];
    if (a >= 0) {
      float l[12];
#pragma unroll
      for (int k = 0; k < 12; k++) l[k] = Lc[a][k];
      float n[12];
#pragma unroll
      for (int r = 0; r < 3; r++) {
        const float gr0 = g[r * 4 + 0], gr1 = g[r * 4 + 1], gr2 = g[r * 4 + 2];
        n[r * 4 + 0] = gr0 * l[0] + gr1 * l[4] + gr2 * l[8];
        n[r * 4 + 1] = gr0 * l[1] + gr1 * l[5] + gr2 * l[9];
        n[r * 4 + 2] = gr0 * l[2] + gr1 * l[6] + gr2 * l[10];
        n[r * 4 + 3] = gr0 * l[3] + gr1 * l[7] + gr2 * l[11] + g[r * 4 + 3];
      }
#pragma unroll
      for (int k = 0; k < 12; k++) g[k] = n[k];
    }
  }
  // subtract rest-pose joint location: t' = t - R_g @ J_hat[j]
  const float jx = J_hat[j * 3 + 0], jy = J_hat[j * 3 + 1], jz = J_hat[j * 3 + 2];
  g[3]  -= g[0] * jx + g[1] * jy + g[2]  * jz;
  g[7]  -= g[4] * jx + g[5] * jy + g[6]  * jz;
  g[11] -= g[8] * jx + g[9] * jy + g[10] * jz;
}

// ---- kernel 1: forward kinematics, FK_BPB batches per block ----
// thread tid -> (local batch = tid>>5, joint = tid&31; joint<24 active)
__global__ __launch_bounds__(FK_BPB * 32) void smpl_fk_kernel(
    const float* __restrict__ J_hat,
    const float* __restrict__ pose,
    float* __restrict__ Gws,   // (B, 24, 12)
    int B)
{
  __shared__ __align__(16) float Lc[FK_BPB][NJ][12];
  const int lb = threadIdx.x >> 5;
  const int j  = threadIdx.x & 31;
  const int b  = blockIdx.x * FK_BPB + lb;
  const bool active = (j < NJ) && (b < B);

  if (active) {
    float L[12];
    fk_local(J_hat, pose, b, j, L);
#pragma unroll
    for (int k = 0; k < 12; k++) Lc[lb][j][k] = L[k];
  }
  __syncthreads();
  if (active) {
    float g[12];
    fk_compose(Lc[lb], J_hat, j, g);
    float* dst = Gws + (size_t)b * (NJ * 12) + j * 12;
#pragma unroll
    for (int k = 0; k < 12; k++) dst[k] = g[k];
  }
}

// ---- kernel 2 (primary): blend, G read via block-uniform (scalar) loads ----
__global__ __launch_bounds__(TPB) void smpl_blend_ws_kernel(
    const float* __restrict__ T_hat,
    const float* __restrict__ weights,
    const float* __restrict__ trans,
    const float* __restrict__ Gws,
    float* __restrict__ out,
    int V)
{
  const int b = blockIdx.y;
  const int tid = threadIdx.x;
  const int v0 = blockIdx.x * VPB + tid * VPT;  // v0 even; V even -> full pairs
  if (v0 >= V) return;

  const float* __restrict__ Gb = Gws + (size_t)b * (NJ * 12);  // block-uniform
  const float* __restrict__ wbase = weights + (size_t)v0 * 24;

  float acc[VPT][12];

#pragma unroll
  for (int jc = 0; jc < 6; jc++) {
    float4 w4[VPT];
#pragma unroll
    for (int i = 0; i < VPT; i++)
      w4[i] = *reinterpret_cast<const float4*>(wbase + i * 24 + jc * 4);
#pragma unroll
    for (int jj = 0; jj < 4; jj++) {
      const int j = jc * 4 + jj;
      // block-uniform addresses -> compiler emits s_load into SGPRs
      const float4 g0 = *reinterpret_cast<const float4*>(Gb + j * 12 + 0);
      const float4 g1 = *reinterpret_cast<const float4*>(Gb + j * 12 + 4);
      const float4 g2 = *reinterpret_cast<const float4*>(Gb + j * 12 + 8);
#pragma unroll
      for (int i = 0; i < VPT; i++) {
        const float w = (jj == 0) ? w4[i].x : (jj == 1) ? w4[i].y
                      : (jj == 2) ? w4[i].z : w4[i].w;
        if (jc == 0 && jj == 0) {
          acc[i][0]  = w * g0.x;  acc[i][1]  = w * g0.y;
          acc[i][2]  = w * g0.z;  acc[i][3]  = w * g0.w;
          acc[i][4]  = w * g1.x;  acc[i][5]  = w * g1.y;
          acc[i][6]  = w * g1.z;  acc[i][7]  = w * g1.w;
          acc[i][8]  = w * g2.x;  acc[i][9]  = w * g2.y;
          acc[i][10] = w * g2.z;  acc[i][11] = w * g2.w;
        } else {
          acc[i][0]  = fmaf(w, g0.x, acc[i][0]);
          acc[i][1]  = fmaf(w, g0.y, acc[i][1]);
          acc[i][2]  = fmaf(w, g0.z, acc[i][2]);
          acc[i][3]  = fmaf(w, g0.w, acc[i][3]);
          acc[i][4]  = fmaf(w, g1.x, acc[i][4]);
          acc[i][5]  = fmaf(w, g1.y, acc[i][5]);
          acc[i][6]  = fmaf(w, g1.z, acc[i][6]);
          acc[i][7]  = fmaf(w, g1.w, acc[i][7]);
          acc[i][8]  = fmaf(w, g2.x, acc[i][8]);
          acc[i][9]  = fmaf(w, g2.y, acc[i][9]);
          acc[i][10] = fmaf(w, g2.z, acc[i][10]);
          acc[i][11] = fmaf(w, g2.w, acc[i][11]);
        }
      }
    }
  }

  const float t0 = trans[b * 3 + 0];
  const float t1 = trans[b * 3 + 1];
  const float t2 = trans[b * 3 + 2];

  // T_hat: 6 floats at 8B alignment -> 3x float2 (coalesced across lanes)
  float th[3 * VPT];
  const float2* tp = reinterpret_cast<const float2*>(T_hat + (size_t)v0 * 3);
#pragma unroll
  for (int q = 0; q < 3; q++) {
    const float2 t = tp[q];
    th[q * 2 + 0] = t.x; th[q * 2 + 1] = t.y;
  }

  float o[3 * VPT];
#pragma unroll
  for (int i = 0; i < VPT; i++) {
    const float x = th[i * 3 + 0], y = th[i * 3 + 1], z = th[i * 3 + 2];
    o[i * 3 + 0] = acc[i][0] * x + acc[i][1] * y + acc[i][2]  * z + acc[i][3]  + t0;
    o[i * 3 + 1] = acc[i][4] * x + acc[i][5] * y + acc[i][6]  * z + acc[i][7]  + t1;
    o[i * 3 + 2] = acc[i][8] * x + acc[i][9] * y + acc[i][10] * z + acc[i][11] + t2;
  }
  float2* op = reinterpret_cast<float2*>(out + (size_t)b * V * 3 + (size_t)v0 * 3);
#pragma unroll
  for (int q = 0; q < 3; q++)
    op[q] = make_float2(o[q * 2 + 0], o[q * 2 + 1]);
}

// ---- fallback blend (ws too small): FK inline + LDS broadcast ----
__global__ __launch_bounds__(TPB) void smpl_blend_lds_kernel(
    const float* __restrict__ T_hat,
    const float* __restrict__ J_hat,
    const float* __restrict__ weights,
    const float* __restrict__ pose,
    const float* __restrict__ trans,
    float* __restrict__ out,
    int V)
{
  __shared__ __align__(16) float Lc[NJ][12];
  __shared__ __align__(16) float Gm[NJ][12];
  const int b = blockIdx.y;
  const int tid = threadIdx.x;

  if (tid < NJ) {
    float L[12];
    fk_local(J_hat, pose, b, tid, L);
#pragma unroll
    for (int k = 0; k < 12; k++) Lc[tid][k] = L[k];
  }
  __syncthreads();
  if (tid < NJ) {
    float g[12];
    fk_compose(Lc, J_hat, tid, g);
#pragma unroll
    for (int k = 0; k < 12; k++) Gm[tid][k] = g[k];
  }
  __syncthreads();

  const int v0 = blockIdx.x * VPB + tid * VPT;
  if (v0 >= V) return;

  const float* wbase = weights + (size_t)v0 * 24;
  float acc[VPT][12];
#pragma unroll
  for (int i = 0; i < VPT; i++)
#pragma unroll
    for (int k = 0; k < 12; k++) acc[i][k] = 0.0f;

#pragma unroll
  for (int jc = 0; jc < 6; jc++) {
    float4 w4[VPT];
#pragma unroll
    for (int i = 0; i < VPT; i++)
      w4[i] = *reinterpret_cast<const float4*>(wbase + i * 24 + jc * 4);
#pragma unroll
    for (int jj = 0; jj < 4; jj++) {
      const int j = jc * 4 + jj;
      const float4 g0 = *reinterpret_cast<const float4*>(&Gm[j][0]);
      const float4 g1 = *reinterpret_cast<const float4*>(&Gm[j][4]);
      const float4 g2 = *reinterpret_cast<const float4*>(&Gm[j][8]);
#pragma unroll
      for (int i = 0; i < VPT; i++) {
        const float w = (jj == 0) ? w4[i].x : (jj == 1) ? w4[i].y
                      : (jj == 2) ? w4[i].z : w4[i].w;
        acc[i][0]  = fmaf(w, g0.x, acc[i][0]);
        acc[i][1]  = fmaf(w, g0.y, acc[i][1]);
        acc[i][2]  = fmaf(w, g0.z, acc[i][2]);
        acc[i][3]  = fmaf(w, g0.w, acc[i][3]);
        acc[i][4]  = fmaf(w, g1.x, acc[i][4]);
        acc[i][5]  = fmaf(w, g1.y, acc[i][5]);
        acc[i][6]  = fmaf(w, g1.z, acc[i][6]);
        acc[i][7]  = fmaf(w, g1.w, acc[i][7]);
        acc[i][8]  = fmaf(w, g2.x, acc[i][8]);
        acc[i][9]  = fmaf(w, g2.y, acc[i][9]);
        acc[i][10] = fmaf(w, g2.z, acc[i][10]);
        acc[i][11] = fmaf(w, g2.w, acc[i][11]);
      }
    }
  }

  const float t0 = trans[b * 3 + 0];
  const float t1 = trans[b * 3 + 1];
  const float t2 = trans[b * 3 + 2];
  float th[3 * VPT];
  const float2* tp = reinterpret_cast<const float2*>(T_hat + (size_t)v0 * 3);
#pragma unroll
  for (int q = 0; q < 3; q++) {
    const float2 t = tp[q];
    th[q * 2 + 0] = t.x; th[q * 2 + 1] = t.y;
  }
  float o[3 * VPT];
#pragma unroll
  for (int i = 0; i < VPT; i++) {
    const float x = th[i * 3 + 0], y = th[i * 3 + 1], z = th[i * 3 + 2];
    o[i * 3 + 0] = acc[i][0] * x + acc[i][1] * y + acc[i][2]  * z + acc[i][3]  + t0;
    o[i * 3 + 1] = acc[i][4] * x + acc[i][5] * y + acc[i][6]  * z + acc[i][7]  + t1;
    o[i * 3 + 2] = acc[i][8] * x + acc[i][9] * y + acc[i][10] * z + acc[i][11] + t2;
  }
  float2* op = reinterpret_cast<float2*>(out + (size_t)b * V * 3 + (size_t)v0 * 3);
#pragma unroll
  for (int q = 0; q < 3; q++)
    op[q] = make_float2(o[q * 2 + 0], o[q * 2 + 1]);
}

extern "C" void kernel_launch(void* const* d_in, const int* in_sizes, int n_in,
                              void* d_out, int out_size, void* d_ws, size_t ws_size,
                              hipStream_t stream) {
  const float* T_hat   = (const float*)d_in[0];
  const float* J_hat   = (const float*)d_in[1];
  const float* weights = (const float*)d_in[2];
  const float* pose    = (const float*)d_in[3];
  const float* trans   = (const float*)d_in[4];
  float* out = (float*)d_out;

  const int V = in_sizes[0] / 3;   // 6890
  const int B = in_sizes[3] / 72;  // 512

  const int nvchunks = (V + VPB - 1) / VPB;  // 14
  dim3 grid(nvchunks, B);

  const size_t ws_needed = (size_t)B * NJ * 12 * sizeof(float);  // 576 KB
  if (ws_size >= ws_needed) {
    float* Gws = (float*)d_ws;
    const int fkblocks = (B + FK_BPB - 1) / FK_BPB;  // 64
    smpl_fk_kernel<<<fkblocks, FK_BPB * 32, 0, stream>>>(J_hat, pose, Gws, B);
    smpl_blend_ws_kernel<<<grid, TPB, 0, stream>>>(
        T_hat, weights, trans, Gws, out, V);
  } else {
    smpl_blend_lds_kernel<<<grid, TPB, 0, stream>>>(
        T_hat, J_hat, weights, pose, trans, out, V);
  }
}